// Round 7
// baseline (588.134 us; speedup 1.0000x reference)
//
#include <hip/hip_runtime.h>
#include <cstdint>
#include <cstddef>

typedef unsigned short u16;
typedef __attribute__((ext_vector_type(8))) short short8;
typedef __attribute__((ext_vector_type(4))) float float4v;

struct alignas(8) u16x4 { u16 x, y, z, w; };

__device__ __forceinline__ float bf2f(u16 u) {
  union { uint32_t i; float f; } x;
  x.i = ((uint32_t)u) << 16;
  return x.f;
}
__device__ __forceinline__ u16 f2bf(float f) {
  union { float f; uint32_t i; } x;
  x.f = f;
  uint32_t r = x.i + 0x7fffu + ((x.i >> 16) & 1u);  // RNE
  return (u16)(r >> 16);
}
// pack 8 fp32 -> 8 bf16 (memory order a.x..a.w,b.x..b.w)
__device__ __forceinline__ int4 pack8(const float4& a, const float4& b) {
  int4 r;
  r.x = (uint32_t)f2bf(a.x) | ((uint32_t)f2bf(a.y) << 16);
  r.y = (uint32_t)f2bf(a.z) | ((uint32_t)f2bf(a.w) << 16);
  r.z = (uint32_t)f2bf(b.x) | ((uint32_t)f2bf(b.y) << 16);
  r.w = (uint32_t)f2bf(b.z) | ((uint32_t)f2bf(b.w) << 16);
  return r;
}

// ---------------------------------------------------------------------------
// GEMM_BT: C[M,N] = A[M,K] * B[N,K]^T, A bf16 (ws), B fp32 (d_in weights,
// converted to bf16 during LDS staging), fp32 accumulate.
// RMODE: 0 = no residual, 1 = fp32 residual, 2 = bf16 residual.
// OUTF32: write float32 (d_out is fp32 per reference output dtype!).
// 128x128 tile, BK=32, 4 waves of 64x64. mfma_f32_16x16x32_bf16 layouts
// (learn_hip m89/m91 verified; r3==r4 equivalence verified on-device):
//   A frag: lane holds A[m = lane&15][k = (lane>>4)*8 + j]
//   B frag: lane holds Bop[k = (lane>>4)*8 + j][n = lane&15]
//   C/D  : row = (lane>>4)*4 + reg, col = lane&15
// ---------------------------------------------------------------------------
#define LDT 40

template <int RMODE, bool OUTF32>
__global__ __launch_bounds__(256) void gemm_bt_kernel(
    const u16* __restrict__ A, const float* __restrict__ B,
    void* __restrict__ Cv, const void* __restrict__ Rv,
    int M, int N, int K)
{
  __shared__ u16 As[128 * LDT];
  __shared__ u16 Bs[128 * LDT];
  const int t = threadIdx.x;
  const int lane = t & 63;
  const int wave = t >> 6;
  const int l15 = lane & 15;
  const int quad = lane >> 4;
  const int wm = (wave >> 1) * 64;
  const int wn = (wave & 1) * 64;
  const int m0 = blockIdx.y * 128;
  const int n0 = blockIdx.x * 128;
  const int arow = t >> 2;
  const int acs = (t & 3) * 8;

  float4v acc[4][4] = {};

  const u16* Ab = A + (size_t)(m0 + arow) * K + acs;
  const float* Bb = B + (size_t)(n0 + arow) * K + acs;
  const size_t rstep = (size_t)64 * K;

  for (int kk = 0; kk < K; kk += 32) {
    int4 a0 = *(const int4*)(Ab + kk);
    int4 a1 = *(const int4*)(Ab + rstep + kk);
    float4 b0a = *(const float4*)(Bb + kk);
    float4 b0b = *(const float4*)(Bb + kk + 4);
    float4 b1a = *(const float4*)(Bb + rstep + kk);
    float4 b1b = *(const float4*)(Bb + rstep + kk + 4);
    *(int4*)(&As[arow * LDT + acs]) = a0;
    *(int4*)(&As[(arow + 64) * LDT + acs]) = a1;
    *(int4*)(&Bs[arow * LDT + acs]) = pack8(b0a, b0b);
    *(int4*)(&Bs[(arow + 64) * LDT + acs]) = pack8(b1a, b1b);
    __syncthreads();
    short8 af[4], bf[4];
#pragma unroll
    for (int i = 0; i < 4; i++)
      af[i] = *(const short8*)(&As[(wm + i * 16 + l15) * LDT + quad * 8]);
#pragma unroll
    for (int j = 0; j < 4; j++)
      bf[j] = *(const short8*)(&Bs[(wn + j * 16 + l15) * LDT + quad * 8]);
#pragma unroll
    for (int i = 0; i < 4; i++)
#pragma unroll
      for (int j = 0; j < 4; j++)
        acc[i][j] = __builtin_amdgcn_mfma_f32_16x16x32_bf16(af[i], bf[j], acc[i][j], 0, 0, 0);
    __syncthreads();
  }

#pragma unroll
  for (int i = 0; i < 4; i++) {
#pragma unroll
    for (int r = 0; r < 4; r++) {
      const int row = m0 + wm + i * 16 + quad * 4 + r;
      const size_t base = (size_t)row * N;
#pragma unroll
      for (int j = 0; j < 4; j++) {
        const int col = n0 + wn + j * 16 + l15;
        float v = acc[i][j][r];
        if (RMODE == 1) v += ((const float*)Rv)[base + col];
        if (RMODE == 2) v += bf2f(((const u16*)Rv)[base + col]);
        if (OUTF32) ((float*)Cv)[base + col] = v;
        else        ((u16*)Cv)[base + col] = f2bf(v);
      }
    }
  }
}

// ---------------------------------------------------------------------------
// Fused FFN up-projection: a = A*W1^T, b = A*W3^T on a shared A tile,
// C = silu(a)*b (bf16). A bf16, W1/W3 fp32. 128x128 tile, BK=32.
// ---------------------------------------------------------------------------
__global__ __launch_bounds__(256) void gemm_w13_kernel(
    const u16* __restrict__ A, const float* __restrict__ B1,
    const float* __restrict__ B2, u16* __restrict__ C,
    int M, int N, int K)
{
  __shared__ u16 As[128 * LDT];
  __shared__ u16 B1s[128 * LDT];
  __shared__ u16 B2s[128 * LDT];
  const int t = threadIdx.x;
  const int lane = t & 63;
  const int wave = t >> 6;
  const int l15 = lane & 15;
  const int quad = lane >> 4;
  const int wm = (wave >> 1) * 64;
  const int wn = (wave & 1) * 64;
  const int m0 = blockIdx.y * 128;
  const int n0 = blockIdx.x * 128;
  const int arow = t >> 2;
  const int acs = (t & 3) * 8;

  float4v accA[4][4] = {};
  float4v accB[4][4] = {};

  const u16* Ab = A + (size_t)(m0 + arow) * K + acs;
  const float* B1b = B1 + (size_t)(n0 + arow) * K + acs;
  const float* B2b = B2 + (size_t)(n0 + arow) * K + acs;
  const size_t rstep = (size_t)64 * K;

  for (int kk = 0; kk < K; kk += 32) {
    int4 a0 = *(const int4*)(Ab + kk);
    int4 a1 = *(const int4*)(Ab + rstep + kk);
    float4 c0a = *(const float4*)(B1b + kk);
    float4 c0b = *(const float4*)(B1b + kk + 4);
    float4 c1a = *(const float4*)(B1b + rstep + kk);
    float4 c1b = *(const float4*)(B1b + rstep + kk + 4);
    float4 d0a = *(const float4*)(B2b + kk);
    float4 d0b = *(const float4*)(B2b + kk + 4);
    float4 d1a = *(const float4*)(B2b + rstep + kk);
    float4 d1b = *(const float4*)(B2b + rstep + kk + 4);
    *(int4*)(&As[arow * LDT + acs]) = a0;
    *(int4*)(&As[(arow + 64) * LDT + acs]) = a1;
    *(int4*)(&B1s[arow * LDT + acs]) = pack8(c0a, c0b);
    *(int4*)(&B1s[(arow + 64) * LDT + acs]) = pack8(c1a, c1b);
    *(int4*)(&B2s[arow * LDT + acs]) = pack8(d0a, d0b);
    *(int4*)(&B2s[(arow + 64) * LDT + acs]) = pack8(d1a, d1b);
    __syncthreads();
    short8 af[4], b1f[4], b2f[4];
#pragma unroll
    for (int i = 0; i < 4; i++)
      af[i] = *(const short8*)(&As[(wm + i * 16 + l15) * LDT + quad * 8]);
#pragma unroll
    for (int j = 0; j < 4; j++) {
      b1f[j] = *(const short8*)(&B1s[(wn + j * 16 + l15) * LDT + quad * 8]);
      b2f[j] = *(const short8*)(&B2s[(wn + j * 16 + l15) * LDT + quad * 8]);
    }
#pragma unroll
    for (int i = 0; i < 4; i++)
#pragma unroll
      for (int j = 0; j < 4; j++) {
        accA[i][j] = __builtin_amdgcn_mfma_f32_16x16x32_bf16(af[i], b1f[j], accA[i][j], 0, 0, 0);
        accB[i][j] = __builtin_amdgcn_mfma_f32_16x16x32_bf16(af[i], b2f[j], accB[i][j], 0, 0, 0);
      }
    __syncthreads();
  }

#pragma unroll
  for (int i = 0; i < 4; i++) {
#pragma unroll
    for (int r = 0; r < 4; r++) {
      const int row = m0 + wm + i * 16 + quad * 4 + r;
      const size_t base = (size_t)row * N;
#pragma unroll
      for (int j = 0; j < 4; j++) {
        const int col = n0 + wn + j * 16 + l15;
        float a = accA[i][j][r];
        float b = accB[i][j][r];
        float h = a / (1.f + __expf(-a)) * b;
        C[base + col] = f2bf(h);
      }
    }
  }
}

// ---------------------------------------------------------------------------
// Causal flash attention (MFMA; proven output-equivalent to the scalar-safe
// version by rounds 3/4 identical absmax). qkv: [B*S, 3072] bf16 rows.
// Block = (b,h,64-query tile), 4 waves; wave w owns queries q0+w*16+l15.
// Transposed-score: S^T[key][q] = K*Q^T -> per-lane softmax state.
// P via per-wave LDS [q][key], then O^T[d][q] += V^T * P^T.
// ---------------------------------------------------------------------------
#define AST 72

__global__ __launch_bounds__(256) void attn_kernel(
    const u16* __restrict__ qkv, u16* __restrict__ outp)
{
  __shared__ u16 Ks[64 * AST];
  __shared__ u16 Vt[64 * AST];
  __shared__ u16 Pl[4 * 16 * AST];
  const int t = threadIdx.x;
  const int lane = t & 63;
  const int wave = t >> 6;
  const int l15 = lane & 15;
  const int quad = lane >> 4;
  const int qt = blockIdx.x;
  const int bh = blockIdx.y;
  const int b = bh >> 4;
  const int h = bh & 15;
  const int q0 = qt * 64;
  const int q = q0 + wave * 16 + l15;
  const size_t srow = (size_t)b * 2048;
  u16* plw = &Pl[wave * 16 * AST];

  short8 qf[2];
  {
    const size_t qbase = (srow + q) * 3072 + h * 64;
#pragma unroll
    for (int dh = 0; dh < 2; dh++) {
      int4 raw = *(const int4*)(qkv + qbase + dh * 32 + quad * 8);
      const u16* rp = (const u16*)&raw;
      short8 f;
#pragma unroll
      for (int j = 0; j < 8; j++)
        ((u16*)&f)[j] = f2bf(bf2f(rp[j]) * 0.125f);
      qf[dh] = f;
    }
  }

  float m_i = -INFINITY;
  float l_i = 0.f;
  float4v accO[4] = {};

  const int skey = t >> 3;
  const int sds = (t & 7) * 8;

  for (int c0 = 0; c0 <= q0; c0 += 64) {
#pragma unroll
    for (int ssg = 0; ssg < 2; ssg++) {
      const int key = skey + ssg * 32;
      const size_t g = (srow + c0 + key) * 3072 + h * 64 + sds;
      int4 kv = *(const int4*)(qkv + g + 1024);
      int4 vv = *(const int4*)(qkv + g + 2048);
      *(int4*)(&Ks[key * AST + sds]) = kv;
      const u16* vp = (const u16*)&vv;
#pragma unroll
      for (int i = 0; i < 8; i++) Vt[(sds + i) * AST + key] = vp[i];
    }
    __syncthreads();

    float4v accS[4];
#pragma unroll
    for (int ks = 0; ks < 4; ks++) {
      short8 kf0 = *(const short8*)(&Ks[(ks * 16 + l15) * AST + quad * 8]);
      short8 kf1 = *(const short8*)(&Ks[(ks * 16 + l15) * AST + 32 + quad * 8]);
      float4v z = {};
      z = __builtin_amdgcn_mfma_f32_16x16x32_bf16(kf0, qf[0], z, 0, 0, 0);
      accS[ks] = __builtin_amdgcn_mfma_f32_16x16x32_bf16(kf1, qf[1], z, 0, 0, 0);
    }

    if (c0 == q0) {
#pragma unroll
      for (int ks = 0; ks < 4; ks++)
#pragma unroll
        for (int r = 0; r < 4; r++)
          if (c0 + ks * 16 + quad * 4 + r > q) accS[ks][r] = -INFINITY;
    }

    float cmax = -INFINITY;
#pragma unroll
    for (int ks = 0; ks < 4; ks++)
#pragma unroll
      for (int r = 0; r < 4; r++) cmax = fmaxf(cmax, accS[ks][r]);
    cmax = fmaxf(cmax, __shfl_xor(cmax, 16));
    cmax = fmaxf(cmax, __shfl_xor(cmax, 32));
    const float mn = fmaxf(m_i, cmax);
    const float alpha = __expf(m_i - mn);

    float psum = 0.f;
#pragma unroll
    for (int ks = 0; ks < 4; ks++) {
      float p0 = __expf(accS[ks][0] - mn);
      float p1 = __expf(accS[ks][1] - mn);
      float p2 = __expf(accS[ks][2] - mn);
      float p3 = __expf(accS[ks][3] - mn);
      psum += (p0 + p1) + (p2 + p3);
      u16x4 pk;
      pk.x = f2bf(p0); pk.y = f2bf(p1); pk.z = f2bf(p2); pk.w = f2bf(p3);
      *(u16x4*)(&plw[l15 * AST + ks * 16 + quad * 4]) = pk;
    }
    psum += __shfl_xor(psum, 16);
    psum += __shfl_xor(psum, 32);
    l_i = l_i * alpha + psum;
    m_i = mn;
#pragma unroll
    for (int ds = 0; ds < 4; ds++)
#pragma unroll
      for (int r = 0; r < 4; r++) accO[ds][r] *= alpha;

    __threadfence_block();

#pragma unroll
    for (int kh = 0; kh < 2; kh++) {
      short8 pf = *(const short8*)(&plw[l15 * AST + kh * 32 + quad * 8]);
#pragma unroll
      for (int ds = 0; ds < 4; ds++) {
        short8 vf = *(const short8*)(&Vt[(ds * 16 + l15) * AST + kh * 32 + quad * 8]);
        accO[ds] = __builtin_amdgcn_mfma_f32_16x16x32_bf16(vf, pf, accO[ds], 0, 0, 0);
      }
    }
    __syncthreads();
  }

  const float invl = 1.f / l_i;
  const size_t obase = (srow + q) * 1024 + h * 64;
#pragma unroll
  for (int ds = 0; ds < 4; ds++) {
    u16x4 pk;
    pk.x = f2bf(accO[ds][0] * invl);
    pk.y = f2bf(accO[ds][1] * invl);
    pk.z = f2bf(accO[ds][2] * invl);
    pk.w = f2bf(accO[ds][3] * invl);
    *(u16x4*)(outp + obase + ds * 16 + quad * 4) = pk;
  }
}

// ---------------------------------------------------------------------------
// RMSNorm over rows of 1024. XF32: x fp32 else bf16. g fp32. Output bf16.
// ---------------------------------------------------------------------------
template <bool XF32>
__global__ __launch_bounds__(256) void rmsnorm_kernel(
    const void* __restrict__ xv, const float* __restrict__ g, u16* __restrict__ o)
{
  const int row = blockIdx.x;
  const int t = threadIdx.x;
  float f0, f1, f2, f3;
  if (XF32) {
    float4 v = *(const float4*)((const float*)xv + (size_t)row * 1024 + t * 4);
    f0 = v.x; f1 = v.y; f2 = v.z; f3 = v.w;
  } else {
    int2 v = *(const int2*)((const u16*)xv + (size_t)row * 1024 + t * 4);
    const u16* p = (const u16*)&v;
    f0 = bf2f(p[0]); f1 = bf2f(p[1]); f2 = bf2f(p[2]); f3 = bf2f(p[3]);
  }
  float ss = f0 * f0 + f1 * f1 + f2 * f2 + f3 * f3;
#pragma unroll
  for (int off = 32; off > 0; off >>= 1) ss += __shfl_down(ss, off);
  __shared__ float red[4];
  if ((t & 63) == 0) red[t >> 6] = ss;
  __syncthreads();
  const float tot = red[0] + red[1] + red[2] + red[3];
  const float inv = rsqrtf(tot * (1.0f / 1024.0f) + 1e-5f);
  float4 gv = *(const float4*)(g + t * 4);
  u16x4 ov;
  ov.x = f2bf(f0 * gv.x * inv);
  ov.y = f2bf(f1 * gv.y * inv);
  ov.z = f2bf(f2 * gv.z * inv);
  ov.w = f2bf(f3 * gv.w * inv);
  *(u16x4*)(o + (size_t)row * 1024 + t * 4) = ov;
}

// ---------------------------------------------------------------------------
// Inputs (fp32, dict order): x:[2,2048,1024] wqkv:[3072,1024] wo:[1024,1024]
// g1,g2:[1024] w1:[2688,1024] w2:[1024,2688] w3:[2688,1024]
// OUTPUT: float32 (reference returns fp32 — verified by r0/r2-r6 absmax
// arithmetic: zero-out=5.31=max|ref|; u16 writes decorrelate to sqrt(2)x).
// Workspace: S1 8MB (xn->att->xn2), S2 24MB (qkv->h), S3 8MB (x1). 40MB.
// ---------------------------------------------------------------------------
extern "C" void kernel_launch(void* const* d_in, const int* in_sizes, int n_in,
                              void* d_out, int out_size, void* d_ws, size_t ws_size,
                              hipStream_t stream)
{
  const float* x    = (const float*)d_in[0];
  const float* wqkv = (const float*)d_in[1];
  const float* wo   = (const float*)d_in[2];
  const float* g1   = (const float*)d_in[3];
  const float* g2   = (const float*)d_in[4];
  const float* w1   = (const float*)d_in[5];
  const float* w2   = (const float*)d_in[6];
  const float* w3   = (const float*)d_in[7];
  float* out = (float*)d_out;
  char* ws = (char*)d_ws;
  (void)in_sizes; (void)n_in; (void)out_size; (void)ws_size;

  const size_t MB8 = (size_t)4096 * 1024 * 2;
  u16* S1 = (u16*)(ws);                    // 8 MB
  u16* S2 = (u16*)(ws + MB8);              // 24 MB
  u16* S3 = (u16*)(ws + MB8 + 3 * MB8);    // 8 MB

  rmsnorm_kernel<true><<<4096, 256, 0, stream>>>(x, g1, S1);                    // xn
  gemm_bt_kernel<0, false><<<dim3(24, 32), 256, 0, stream>>>(S1, wqkv, S2,
                                            nullptr, 4096, 3072, 1024);         // qkv
  attn_kernel<<<dim3(32, 32), 256, 0, stream>>>(S2, S1);                        // att
  gemm_bt_kernel<1, false><<<dim3(8, 32), 256, 0, stream>>>(S1, wo, S3, x,
                                            4096, 1024, 1024);                  // x1
  rmsnorm_kernel<false><<<4096, 256, 0, stream>>>(S3, g2, S1);                  // xn2
  gemm_w13_kernel<<<dim3(21, 32), 256, 0, stream>>>(S1, w1, w3, S2,
                                            4096, 2688, 1024);                  // h
  gemm_bt_kernel<2, true><<<dim3(8, 32), 256, 0, stream>>>(S2, w2, out, S3,
                                            4096, 1024, 2688);                  // out fp32
}

// Round 8
// 468.670 us; speedup vs baseline: 1.2549x; 1.2549x over previous
//
#include <hip/hip_runtime.h>
#include <cstdint>
#include <cstddef>

typedef unsigned short u16;
typedef __attribute__((ext_vector_type(8))) short short8;
typedef __attribute__((ext_vector_type(4))) float float4v;

struct alignas(8) u16x4 { u16 x, y, z, w; };

__device__ __forceinline__ float bf2f(u16 u) {
  union { uint32_t i; float f; } x;
  x.i = ((uint32_t)u) << 16;
  return x.f;
}
__device__ __forceinline__ u16 f2bf(float f) {
  union { float f; uint32_t i; } x;
  x.f = f;
  uint32_t r = x.i + 0x7fffu + ((x.i >> 16) & 1u);  // RNE
  return (u16)(r >> 16);
}
// pack 8 fp32 -> 8 bf16 (memory order)
__device__ __forceinline__ int4 pack8(const float4& a, const float4& b) {
  int4 r;
  r.x = (uint32_t)f2bf(a.x) | ((uint32_t)f2bf(a.y) << 16);
  r.y = (uint32_t)f2bf(a.z) | ((uint32_t)f2bf(a.w) << 16);
  r.z = (uint32_t)f2bf(b.x) | ((uint32_t)f2bf(b.y) << 16);
  r.w = (uint32_t)f2bf(b.z) | ((uint32_t)f2bf(b.w) << 16);
  return r;
}

// async global->LDS, 16 B per lane; LDS dest = wave-uniform base + lane*16.
__device__ __forceinline__ void gload_lds16(const void* g, void* l) {
  __builtin_amdgcn_global_load_lds(
      (const __attribute__((address_space(1))) void*)g,
      (__attribute__((address_space(3))) void*)l, 16, 0, 0);
}

// ---------------------------------------------------------------------------
// Weight prep: fp32 -> bf16 for the 5 weight matrices (one kernel).
// ---------------------------------------------------------------------------
struct PrepArgs {
  const float* src[5];
  u16* dst[5];
  int pre[6];   // prefix sums of 8-elem group counts
};

__global__ __launch_bounds__(256) void prep_kernel(PrepArgs a)
{
  const int g = blockIdx.x * 256 + threadIdx.x;
  if (g >= a.pre[5]) return;
  int t = 0;
#pragma unroll
  for (int i = 0; i < 5; i++) if (g >= a.pre[i + 1]) t = i + 1;
  const int idx = (g - a.pre[t]) * 8;
  const float* s = a.src[t] + idx;
  float4 v0 = *(const float4*)(s);
  float4 v1 = *(const float4*)(s + 4);
  *(int4*)(a.dst[t] + idx) = pack8(v0, v1);
}

// ---------------------------------------------------------------------------
// GEMM_BT: C[M,N] = A[M,K] (bf16) * B[N,K]^T (bf16), fp32 acc.
// RMODE: 0 none, 1 fp32 residual, 2 bf16 residual. OUTF32: fp32 C (d_out).
// TN: 128 (4x4 acc/wave) or 64 (4x2 acc/wave; for N=1024 GEMMs -> 512 blocks).
// m97 structure: global_load_lds width-16 staging, BK=32, 128xTN tile,
// 4 waves of 64x(TN/2). LDS layout: packed 32-elem rows, XOR segment swizzle
//   slot(row, q) = row*4 + (q ^ ((row>>1)&3))
// -> DMA-compatible (no padding) and ds_read_b128 fragment reads are 2-way
// bank-aliased (free, m136). Fragment<->MFMA mapping unchanged from the
// pass-verified r7 kernel:
//   A frag: lane holds A[m=lane&15][k=(lane>>4)*8+j]
//   B frag: lane holds Bop[k=(lane>>4)*8+j][n=lane&15]
//   C/D  : row=(lane>>4)*4+reg, col=lane&15
// ---------------------------------------------------------------------------
template <int RMODE, bool OUTF32, int TN>
__global__ __launch_bounds__(256) void gemm_bt_kernel(
    const u16* __restrict__ A, const u16* __restrict__ B,
    void* __restrict__ Cv, const void* __restrict__ Rv,
    int M, int N, int K)
{
  constexpr int JN = TN / 32;          // N-subtiles per wave (4 or 2)
  __shared__ u16 As[128 * 32];
  __shared__ u16 Bs[TN * 32];
  const int t = threadIdx.x;
  const int lane = t & 63;
  const int wave = t >> 6;
  const int l15 = lane & 15;
  const int quad = lane >> 4;
  const int wm = (wave >> 1) * 64;
  const int wn = (wave & 1) * (TN / 2);
  const int m0 = blockIdx.y * 128;
  const int n0 = blockIdx.x * TN;
  const int sw = quad ^ ((l15 >> 1) & 3);   // read-side swizzle selector

  float4v acc[4][JN] = {};

  // staging descriptors (slot s: row = s>>2, global segment q = (s&3)^((s>>3)&3))
  const int r0 = t >> 2, q0s = (t & 3) ^ ((t >> 3) & 3);
  const int s1 = 256 + t;
  const int r1 = s1 >> 2, q1s = (s1 & 3) ^ ((s1 >> 3) & 3);

  for (int kk = 0; kk < K; kk += 32) {
    gload_lds16(A + (size_t)(m0 + r0) * K + kk + q0s * 8, &As[(wave * 64) * 8]);
    gload_lds16(A + (size_t)(m0 + r1) * K + kk + q1s * 8, &As[(256 + wave * 64) * 8]);
    gload_lds16(B + (size_t)(n0 + r0) * K + kk + q0s * 8, &Bs[(wave * 64) * 8]);
    if (TN == 128)
      gload_lds16(B + (size_t)(n0 + r1) * K + kk + q1s * 8, &Bs[(256 + wave * 64) * 8]);
    __syncthreads();
    short8 af[4], bf[JN];
#pragma unroll
    for (int i = 0; i < 4; i++)
      af[i] = *(const short8*)(&As[((wm + i * 16 + l15) * 4 + sw) * 8]);
#pragma unroll
    for (int j = 0; j < JN; j++)
      bf[j] = *(const short8*)(&Bs[((wn + j * 16 + l15) * 4 + sw) * 8]);
#pragma unroll
    for (int i = 0; i < 4; i++)
#pragma unroll
      for (int j = 0; j < JN; j++)
        acc[i][j] = __builtin_amdgcn_mfma_f32_16x16x32_bf16(af[i], bf[j], acc[i][j], 0, 0, 0);
    __syncthreads();
  }

#pragma unroll
  for (int i = 0; i < 4; i++) {
#pragma unroll
    for (int r = 0; r < 4; r++) {
      const int row = m0 + wm + i * 16 + quad * 4 + r;
      const size_t base = (size_t)row * N;
#pragma unroll
      for (int j = 0; j < JN; j++) {
        const int col = n0 + wn + j * 16 + l15;
        float v = acc[i][j][r];
        if (RMODE == 1) v += ((const float*)Rv)[base + col];
        if (RMODE == 2) v += bf2f(((const u16*)Rv)[base + col]);
        if (OUTF32) ((float*)Cv)[base + col] = v;
        else        ((u16*)Cv)[base + col] = f2bf(v);
      }
    }
  }
}

// ---------------------------------------------------------------------------
// Fused FFN up-projection: a = A*W1^T, b = A*W3^T (shared A tile),
// C = silu(a)*b (bf16). Same m97 staging/swizzle; 128x128 tile.
// ---------------------------------------------------------------------------
__global__ __launch_bounds__(256) void gemm_w13_kernel(
    const u16* __restrict__ A, const u16* __restrict__ B1,
    const u16* __restrict__ B2, u16* __restrict__ C,
    int M, int N, int K)
{
  __shared__ u16 As[128 * 32];
  __shared__ u16 B1s[128 * 32];
  __shared__ u16 B2s[128 * 32];
  const int t = threadIdx.x;
  const int lane = t & 63;
  const int wave = t >> 6;
  const int l15 = lane & 15;
  const int quad = lane >> 4;
  const int wm = (wave >> 1) * 64;
  const int wn = (wave & 1) * 64;
  const int m0 = blockIdx.y * 128;
  const int n0 = blockIdx.x * 128;
  const int sw = quad ^ ((l15 >> 1) & 3);

  float4v accA[4][4] = {};
  float4v accB[4][4] = {};

  const int r0 = t >> 2, q0s = (t & 3) ^ ((t >> 3) & 3);
  const int s1 = 256 + t;
  const int r1 = s1 >> 2, q1s = (s1 & 3) ^ ((s1 >> 3) & 3);

  for (int kk = 0; kk < K; kk += 32) {
    gload_lds16(A + (size_t)(m0 + r0) * K + kk + q0s * 8, &As[(wave * 64) * 8]);
    gload_lds16(A + (size_t)(m0 + r1) * K + kk + q1s * 8, &As[(256 + wave * 64) * 8]);
    gload_lds16(B1 + (size_t)(n0 + r0) * K + kk + q0s * 8, &B1s[(wave * 64) * 8]);
    gload_lds16(B1 + (size_t)(n0 + r1) * K + kk + q1s * 8, &B1s[(256 + wave * 64) * 8]);
    gload_lds16(B2 + (size_t)(n0 + r0) * K + kk + q0s * 8, &B2s[(wave * 64) * 8]);
    gload_lds16(B2 + (size_t)(n0 + r1) * K + kk + q1s * 8, &B2s[(256 + wave * 64) * 8]);
    __syncthreads();
    short8 af[4], b1f[4], b2f[4];
#pragma unroll
    for (int i = 0; i < 4; i++)
      af[i] = *(const short8*)(&As[((wm + i * 16 + l15) * 4 + sw) * 8]);
#pragma unroll
    for (int j = 0; j < 4; j++) {
      b1f[j] = *(const short8*)(&B1s[((wn + j * 16 + l15) * 4 + sw) * 8]);
      b2f[j] = *(const short8*)(&B2s[((wn + j * 16 + l15) * 4 + sw) * 8]);
    }
#pragma unroll
    for (int i = 0; i < 4; i++)
#pragma unroll
      for (int j = 0; j < 4; j++) {
        accA[i][j] = __builtin_amdgcn_mfma_f32_16x16x32_bf16(af[i], b1f[j], accA[i][j], 0, 0, 0);
        accB[i][j] = __builtin_amdgcn_mfma_f32_16x16x32_bf16(af[i], b2f[j], accB[i][j], 0, 0, 0);
      }
    __syncthreads();
  }

#pragma unroll
  for (int i = 0; i < 4; i++) {
#pragma unroll
    for (int r = 0; r < 4; r++) {
      const int row = m0 + wm + i * 16 + quad * 4 + r;
      const size_t base = (size_t)row * N;
#pragma unroll
      for (int j = 0; j < 4; j++) {
        const int col = n0 + wn + j * 16 + l15;
        float a = accA[i][j][r];
        float b = accB[i][j][r];
        float h = a / (1.f + __expf(-a)) * b;
        C[base + col] = f2bf(h);
      }
    }
  }
}

// ---------------------------------------------------------------------------
// Causal flash attention — UNCHANGED from the pass-verified round-7 kernel.
// ---------------------------------------------------------------------------
#define AST 72

__global__ __launch_bounds__(256) void attn_kernel(
    const u16* __restrict__ qkv, u16* __restrict__ outp)
{
  __shared__ u16 Ks[64 * AST];
  __shared__ u16 Vt[64 * AST];
  __shared__ u16 Pl[4 * 16 * AST];
  const int t = threadIdx.x;
  const int lane = t & 63;
  const int wave = t >> 6;
  const int l15 = lane & 15;
  const int quad = lane >> 4;
  const int qt = blockIdx.x;
  const int bh = blockIdx.y;
  const int b = bh >> 4;
  const int h = bh & 15;
  const int q0 = qt * 64;
  const int q = q0 + wave * 16 + l15;
  const size_t srow = (size_t)b * 2048;
  u16* plw = &Pl[wave * 16 * AST];

  short8 qf[2];
  {
    const size_t qbase = (srow + q) * 3072 + h * 64;
#pragma unroll
    for (int dh = 0; dh < 2; dh++) {
      int4 raw = *(const int4*)(qkv + qbase + dh * 32 + quad * 8);
      const u16* rp = (const u16*)&raw;
      short8 f;
#pragma unroll
      for (int j = 0; j < 8; j++)
        ((u16*)&f)[j] = f2bf(bf2f(rp[j]) * 0.125f);
      qf[dh] = f;
    }
  }

  float m_i = -INFINITY;
  float l_i = 0.f;
  float4v accO[4] = {};

  const int skey = t >> 3;
  const int sds = (t & 7) * 8;

  for (int c0 = 0; c0 <= q0; c0 += 64) {
#pragma unroll
    for (int ssg = 0; ssg < 2; ssg++) {
      const int key = skey + ssg * 32;
      const size_t g = (srow + c0 + key) * 3072 + h * 64 + sds;
      int4 kv = *(const int4*)(qkv + g + 1024);
      int4 vv = *(const int4*)(qkv + g + 2048);
      *(int4*)(&Ks[key * AST + sds]) = kv;
      const u16* vp = (const u16*)&vv;
#pragma unroll
      for (int i = 0; i < 8; i++) Vt[(sds + i) * AST + key] = vp[i];
    }
    __syncthreads();

    float4v accS[4];
#pragma unroll
    for (int ks = 0; ks < 4; ks++) {
      short8 kf0 = *(const short8*)(&Ks[(ks * 16 + l15) * AST + quad * 8]);
      short8 kf1 = *(const short8*)(&Ks[(ks * 16 + l15) * AST + 32 + quad * 8]);
      float4v z = {};
      z = __builtin_amdgcn_mfma_f32_16x16x32_bf16(kf0, qf[0], z, 0, 0, 0);
      accS[ks] = __builtin_amdgcn_mfma_f32_16x16x32_bf16(kf1, qf[1], z, 0, 0, 0);
    }

    if (c0 == q0) {
#pragma unroll
      for (int ks = 0; ks < 4; ks++)
#pragma unroll
        for (int r = 0; r < 4; r++)
          if (c0 + ks * 16 + quad * 4 + r > q) accS[ks][r] = -INFINITY;
    }

    float cmax = -INFINITY;
#pragma unroll
    for (int ks = 0; ks < 4; ks++)
#pragma unroll
      for (int r = 0; r < 4; r++) cmax = fmaxf(cmax, accS[ks][r]);
    cmax = fmaxf(cmax, __shfl_xor(cmax, 16));
    cmax = fmaxf(cmax, __shfl_xor(cmax, 32));
    const float mn = fmaxf(m_i, cmax);
    const float alpha = __expf(m_i - mn);

    float psum = 0.f;
#pragma unroll
    for (int ks = 0; ks < 4; ks++) {
      float p0 = __expf(accS[ks][0] - mn);
      float p1 = __expf(accS[ks][1] - mn);
      float p2 = __expf(accS[ks][2] - mn);
      float p3 = __expf(accS[ks][3] - mn);
      psum += (p0 + p1) + (p2 + p3);
      u16x4 pk;
      pk.x = f2bf(p0); pk.y = f2bf(p1); pk.z = f2bf(p2); pk.w = f2bf(p3);
      *(u16x4*)(&plw[l15 * AST + ks * 16 + quad * 4]) = pk;
    }
    psum += __shfl_xor(psum, 16);
    psum += __shfl_xor(psum, 32);
    l_i = l_i * alpha + psum;
    m_i = mn;
#pragma unroll
    for (int ds = 0; ds < 4; ds++)
#pragma unroll
      for (int r = 0; r < 4; r++) accO[ds][r] *= alpha;

    __threadfence_block();

#pragma unroll
    for (int kh = 0; kh < 2; kh++) {
      short8 pf = *(const short8*)(&plw[l15 * AST + kh * 32 + quad * 8]);
#pragma unroll
      for (int ds = 0; ds < 4; ds++) {
        short8 vf = *(const short8*)(&Vt[(ds * 16 + l15) * AST + kh * 32 + quad * 8]);
        accO[ds] = __builtin_amdgcn_mfma_f32_16x16x32_bf16(vf, pf, accO[ds], 0, 0, 0);
      }
    }
    __syncthreads();
  }

  const float invl = 1.f / l_i;
  const size_t obase = (srow + q) * 1024 + h * 64;
#pragma unroll
  for (int ds = 0; ds < 4; ds++) {
    u16x4 pk;
    pk.x = f2bf(accO[ds][0] * invl);
    pk.y = f2bf(accO[ds][1] * invl);
    pk.z = f2bf(accO[ds][2] * invl);
    pk.w = f2bf(accO[ds][3] * invl);
    *(u16x4*)(outp + obase + ds * 16 + quad * 4) = pk;
  }
}

// ---------------------------------------------------------------------------
// RMSNorm over rows of 1024 — UNCHANGED from round 7.
// ---------------------------------------------------------------------------
template <bool XF32>
__global__ __launch_bounds__(256) void rmsnorm_kernel(
    const void* __restrict__ xv, const float* __restrict__ g, u16* __restrict__ o)
{
  const int row = blockIdx.x;
  const int t = threadIdx.x;
  float f0, f1, f2, f3;
  if (XF32) {
    float4 v = *(const float4*)((const float*)xv + (size_t)row * 1024 + t * 4);
    f0 = v.x; f1 = v.y; f2 = v.z; f3 = v.w;
  } else {
    int2 v = *(const int2*)((const u16*)xv + (size_t)row * 1024 + t * 4);
    const u16* p = (const u16*)&v;
    f0 = bf2f(p[0]); f1 = bf2f(p[1]); f2 = bf2f(p[2]); f3 = bf2f(p[3]);
  }
  float ss = f0 * f0 + f1 * f1 + f2 * f2 + f3 * f3;
#pragma unroll
  for (int off = 32; off > 0; off >>= 1) ss += __shfl_down(ss, off);
  __shared__ float red[4];
  if ((t & 63) == 0) red[t >> 6] = ss;
  __syncthreads();
  const float tot = red[0] + red[1] + red[2] + red[3];
  const float inv = rsqrtf(tot * (1.0f / 1024.0f) + 1e-5f);
  float4 gv = *(const float4*)(g + t * 4);
  u16x4 ov;
  ov.x = f2bf(f0 * gv.x * inv);
  ov.y = f2bf(f1 * gv.y * inv);
  ov.z = f2bf(f2 * gv.z * inv);
  ov.w = f2bf(f3 * gv.w * inv);
  *(u16x4*)(o + (size_t)row * 1024 + t * 4) = ov;
}

// ---------------------------------------------------------------------------
// Inputs (fp32, dict order): x wqkv wo g1 g2 w1 w2 w3. OUTPUT: fp32.
// ws (64 MB): bf16 weights (24 MB) + S1 8 (xn->att->xn2) + S2 24 (qkv->h)
// + S3 8 (x1).
// ---------------------------------------------------------------------------
extern "C" void kernel_launch(void* const* d_in, const int* in_sizes, int n_in,
                              void* d_out, int out_size, void* d_ws, size_t ws_size,
                              hipStream_t stream)
{
  const float* x    = (const float*)d_in[0];
  const float* wqkv = (const float*)d_in[1];
  const float* wo   = (const float*)d_in[2];
  const float* g1   = (const float*)d_in[3];
  const float* g2   = (const float*)d_in[4];
  const float* w1   = (const float*)d_in[5];
  const float* w2   = (const float*)d_in[6];
  const float* w3   = (const float*)d_in[7];
  float* out = (float*)d_out;
  char* ws = (char*)d_ws;
  (void)in_sizes; (void)n_in; (void)out_size; (void)ws_size;

  size_t off = 0;
  auto alloc = [&](size_t bytes) { void* p = ws + off; off += (bytes + 255) & ~(size_t)255; return p; };
  u16* wqkvb = (u16*)alloc((size_t)3072 * 1024 * 2);
  u16* wob   = (u16*)alloc((size_t)1024 * 1024 * 2);
  u16* w1b   = (u16*)alloc((size_t)2688 * 1024 * 2);
  u16* w2b   = (u16*)alloc((size_t)2688 * 1024 * 2);
  u16* w3b   = (u16*)alloc((size_t)2688 * 1024 * 2);
  u16* S1    = (u16*)alloc((size_t)4096 * 1024 * 2);
  u16* S2    = (u16*)alloc((size_t)4096 * 3072 * 2);
  u16* S3    = (u16*)alloc((size_t)4096 * 1024 * 2);

  // weight conversion
  PrepArgs pa;
  const float* srcs[5] = {wqkv, wo, w1, w2, w3};
  u16* dsts[5] = {wqkvb, wob, w1b, w2b, w3b};
  const int nelem[5] = {3072 * 1024, 1024 * 1024, 2688 * 1024, 2688 * 1024, 2688 * 1024};
  int pre = 0;
  for (int i = 0; i < 5; i++) {
    pa.src[i] = srcs[i];
    pa.dst[i] = dsts[i];
    pa.pre[i] = pre;
    pre += nelem[i] / 8;
  }
  pa.pre[5] = pre;
  prep_kernel<<<(pre + 255) / 256, 256, 0, stream>>>(pa);

  rmsnorm_kernel<true><<<4096, 256, 0, stream>>>(x, g1, S1);                        // xn
  gemm_bt_kernel<0, false, 128><<<dim3(24, 32), 256, 0, stream>>>(S1, wqkvb, S2,
                                                  nullptr, 4096, 3072, 1024);       // qkv
  attn_kernel<<<dim3(32, 32), 256, 0, stream>>>(S2, S1);                            // att
  gemm_bt_kernel<1, false, 64><<<dim3(16, 32), 256, 0, stream>>>(S1, wob, S3, x,
                                                  4096, 1024, 1024);                // x1
  rmsnorm_kernel<false><<<4096, 256, 0, stream>>>(S3, g2, S1);                      // xn2
  gemm_w13_kernel<<<dim3(21, 32), 256, 0, stream>>>(S1, w1b, w3b, S2,
                                                  4096, 2688, 1024);                // h
  gemm_bt_kernel<2, true, 64><<<dim3(16, 32), 256, 0, stream>>>(S2, w2b, out, S3,
                                                  4096, 1024, 2688);                // out fp32
}

// Round 9
// 402.607 us; speedup vs baseline: 1.4608x; 1.1641x over previous
//
#include <hip/hip_runtime.h>
#include <cstdint>
#include <cstddef>

typedef unsigned short u16;
typedef __attribute__((ext_vector_type(8))) short short8;
typedef __attribute__((ext_vector_type(4))) float float4v;

struct alignas(8) u16x4 { u16 x, y, z, w; };

__device__ __forceinline__ float bf2f(u16 u) {
  union { uint32_t i; float f; } x;
  x.i = ((uint32_t)u) << 16;
  return x.f;
}
__device__ __forceinline__ u16 f2bf(float f) {
  union { float f; uint32_t i; } x;
  x.f = f;
  uint32_t r = x.i + 0x7fffu + ((x.i >> 16) & 1u);  // RNE
  return (u16)(r >> 16);
}
__device__ __forceinline__ int4 pack8(const float4& a, const float4& b) {
  int4 r;
  r.x = (uint32_t)f2bf(a.x) | ((uint32_t)f2bf(a.y) << 16);
  r.y = (uint32_t)f2bf(a.z) | ((uint32_t)f2bf(a.w) << 16);
  r.z = (uint32_t)f2bf(b.x) | ((uint32_t)f2bf(b.y) << 16);
  r.w = (uint32_t)f2bf(b.z) | ((uint32_t)f2bf(b.w) << 16);
  return r;
}

// async global->LDS, 16 B per lane; LDS dest = wave-uniform base + lane*16.
__device__ __forceinline__ void gload_lds16(const void* g, void* l) {
  __builtin_amdgcn_global_load_lds(
      (const __attribute__((address_space(1))) void*)g,
      (__attribute__((address_space(3))) void*)l, 16, 0, 0);
}

// ---------------------------------------------------------------------------
// Weight prep: fp32 -> bf16 for the 5 weight matrices. UNCHANGED from r8.
// ---------------------------------------------------------------------------
struct PrepArgs {
  const float* src[5];
  u16* dst[5];
  int pre[6];
};

__global__ __launch_bounds__(256) void prep_kernel(PrepArgs a)
{
  const int g = blockIdx.x * 256 + threadIdx.x;
  if (g >= a.pre[5]) return;
  int t = 0;
#pragma unroll
  for (int i = 0; i < 5; i++) if (g >= a.pre[i + 1]) t = i + 1;
  const int idx = (g - a.pre[t]) * 8;
  const float* s = a.src[t] + idx;
  float4 v0 = *(const float4*)(s);
  float4 v1 = *(const float4*)(s + 4);
  *(int4*)(a.dst[t] + idx) = pack8(v0, v1);
}

// ---------------------------------------------------------------------------
// GEMM_BT — UNCHANGED from r8 (m97 structure, global_load_lds, XOR swizzle).
// ---------------------------------------------------------------------------
template <int RMODE, bool OUTF32, int TN>
__global__ __launch_bounds__(256) void gemm_bt_kernel(
    const u16* __restrict__ A, const u16* __restrict__ B,
    void* __restrict__ Cv, const void* __restrict__ Rv,
    int M, int N, int K)
{
  constexpr int JN = TN / 32;
  __shared__ u16 As[128 * 32];
  __shared__ u16 Bs[TN * 32];
  const int t = threadIdx.x;
  const int lane = t & 63;
  const int wave = t >> 6;
  const int l15 = lane & 15;
  const int quad = lane >> 4;
  const int wm = (wave >> 1) * 64;
  const int wn = (wave & 1) * (TN / 2);
  const int m0 = blockIdx.y * 128;
  const int n0 = blockIdx.x * TN;
  const int sw = quad ^ ((l15 >> 1) & 3);

  float4v acc[4][JN] = {};

  const int r0 = t >> 2, q0s = (t & 3) ^ ((t >> 3) & 3);
  const int s1 = 256 + t;
  const int r1 = s1 >> 2, q1s = (s1 & 3) ^ ((s1 >> 3) & 3);

  for (int kk = 0; kk < K; kk += 32) {
    gload_lds16(A + (size_t)(m0 + r0) * K + kk + q0s * 8, &As[(wave * 64) * 8]);
    gload_lds16(A + (size_t)(m0 + r1) * K + kk + q1s * 8, &As[(256 + wave * 64) * 8]);
    gload_lds16(B + (size_t)(n0 + r0) * K + kk + q0s * 8, &Bs[(wave * 64) * 8]);
    if (TN == 128)
      gload_lds16(B + (size_t)(n0 + r1) * K + kk + q1s * 8, &Bs[(256 + wave * 64) * 8]);
    __syncthreads();
    short8 af[4], bf[JN];
#pragma unroll
    for (int i = 0; i < 4; i++)
      af[i] = *(const short8*)(&As[((wm + i * 16 + l15) * 4 + sw) * 8]);
#pragma unroll
    for (int j = 0; j < JN; j++)
      bf[j] = *(const short8*)(&Bs[((wn + j * 16 + l15) * 4 + sw) * 8]);
#pragma unroll
    for (int i = 0; i < 4; i++)
#pragma unroll
      for (int j = 0; j < JN; j++)
        acc[i][j] = __builtin_amdgcn_mfma_f32_16x16x32_bf16(af[i], bf[j], acc[i][j], 0, 0, 0);
    __syncthreads();
  }

#pragma unroll
  for (int i = 0; i < 4; i++) {
#pragma unroll
    for (int r = 0; r < 4; r++) {
      const int row = m0 + wm + i * 16 + quad * 4 + r;
      const size_t base = (size_t)row * N;
#pragma unroll
      for (int j = 0; j < JN; j++) {
        const int col = n0 + wn + j * 16 + l15;
        float v = acc[i][j][r];
        if (RMODE == 1) v += ((const float*)Rv)[base + col];
        if (RMODE == 2) v += bf2f(((const u16*)Rv)[base + col]);
        if (OUTF32) ((float*)Cv)[base + col] = v;
        else        ((u16*)Cv)[base + col] = f2bf(v);
      }
    }
  }
}

// ---------------------------------------------------------------------------
// Fused FFN up-projection — UNCHANGED from r8.
// ---------------------------------------------------------------------------
__global__ __launch_bounds__(256) void gemm_w13_kernel(
    const u16* __restrict__ A, const u16* __restrict__ B1,
    const u16* __restrict__ B2, u16* __restrict__ C,
    int M, int N, int K)
{
  __shared__ u16 As[128 * 32];
  __shared__ u16 B1s[128 * 32];
  __shared__ u16 B2s[128 * 32];
  const int t = threadIdx.x;
  const int lane = t & 63;
  const int wave = t >> 6;
  const int l15 = lane & 15;
  const int quad = lane >> 4;
  const int wm = (wave >> 1) * 64;
  const int wn = (wave & 1) * 64;
  const int m0 = blockIdx.y * 128;
  const int n0 = blockIdx.x * 128;
  const int sw = quad ^ ((l15 >> 1) & 3);

  float4v accA[4][4] = {};
  float4v accB[4][4] = {};

  const int r0 = t >> 2, q0s = (t & 3) ^ ((t >> 3) & 3);
  const int s1 = 256 + t;
  const int r1 = s1 >> 2, q1s = (s1 & 3) ^ ((s1 >> 3) & 3);

  for (int kk = 0; kk < K; kk += 32) {
    gload_lds16(A + (size_t)(m0 + r0) * K + kk + q0s * 8, &As[(wave * 64) * 8]);
    gload_lds16(A + (size_t)(m0 + r1) * K + kk + q1s * 8, &As[(256 + wave * 64) * 8]);
    gload_lds16(B1 + (size_t)(n0 + r0) * K + kk + q0s * 8, &B1s[(wave * 64) * 8]);
    gload_lds16(B1 + (size_t)(n0 + r1) * K + kk + q1s * 8, &B1s[(256 + wave * 64) * 8]);
    gload_lds16(B2 + (size_t)(n0 + r0) * K + kk + q0s * 8, &B2s[(wave * 64) * 8]);
    gload_lds16(B2 + (size_t)(n0 + r1) * K + kk + q1s * 8, &B2s[(256 + wave * 64) * 8]);
    __syncthreads();
    short8 af[4], b1f[4], b2f[4];
#pragma unroll
    for (int i = 0; i < 4; i++)
      af[i] = *(const short8*)(&As[((wm + i * 16 + l15) * 4 + sw) * 8]);
#pragma unroll
    for (int j = 0; j < 4; j++) {
      b1f[j] = *(const short8*)(&B1s[((wn + j * 16 + l15) * 4 + sw) * 8]);
      b2f[j] = *(const short8*)(&B2s[((wn + j * 16 + l15) * 4 + sw) * 8]);
    }
#pragma unroll
    for (int i = 0; i < 4; i++)
#pragma unroll
      for (int j = 0; j < 4; j++) {
        accA[i][j] = __builtin_amdgcn_mfma_f32_16x16x32_bf16(af[i], b1f[j], accA[i][j], 0, 0, 0);
        accB[i][j] = __builtin_amdgcn_mfma_f32_16x16x32_bf16(af[i], b2f[j], accB[i][j], 0, 0, 0);
      }
    __syncthreads();
  }

#pragma unroll
  for (int i = 0; i < 4; i++) {
#pragma unroll
    for (int r = 0; r < 4; r++) {
      const int row = m0 + wm + i * 16 + quad * 4 + r;
      const size_t base = (size_t)row * N;
#pragma unroll
      for (int j = 0; j < 4; j++) {
        const int col = n0 + wn + j * 16 + l15;
        float a = accA[i][j][r];
        float b = accB[i][j][r];
        float h = a / (1.f + __expf(-a)) * b;
        C[base + col] = f2bf(h);
      }
    }
  }
}

// ---------------------------------------------------------------------------
// V transpose: qkv [s][2048 + h*64 + d] -> VtG [bh][d][s]. LDS-tiled, one-off.
// Grid (32 s-tiles, 32 bh), 256 threads.
// ---------------------------------------------------------------------------
__global__ __launch_bounds__(256) void vtrans_kernel(
    const u16* __restrict__ qkv, u16* __restrict__ VtG)
{
  __shared__ u16 T[64 * 72];
  const int t = threadIdx.x;
  const int s0 = blockIdx.x * 64;
  const int bh = blockIdx.y, b = bh >> 4, h = bh & 15;
  {
    const int sl = t >> 2, dseg = (t & 3) * 16;
    const size_t src = ((size_t)b * 2048 + s0 + sl) * 3072 + 2048 + h * 64 + dseg;
    int4 v0 = *(const int4*)(qkv + src);
    int4 v1 = *(const int4*)(qkv + src + 8);
    *(int4*)(&T[sl * 72 + dseg]) = v0;
    *(int4*)(&T[sl * 72 + dseg + 8]) = v1;
  }
  __syncthreads();
  {
    const int d = t >> 2, sseg = (t & 3) * 16;
    alignas(16) u16 buf[16];
#pragma unroll
    for (int i = 0; i < 16; i++) buf[i] = T[(sseg + i) * 72 + d];
    u16* dst = VtG + ((size_t)bh * 64 + d) * 2048 + s0 + sseg;
    *(int4*)(dst) = *(const int4*)(&buf[0]);
    *(int4*)(dst + 8) = *(const int4*)(&buf[8]);
  }
}

// ---------------------------------------------------------------------------
// Causal flash attention v2.
// Block = (pair, bh): processes q-tiles qt=pair and qt=31-pair sequentially
// -> exactly 17 chunks of 128 keys per block (perfect balance), 512 blocks.
// 4 waves x 16 queries. K staged from qkv (2 d-halves, [128][32] XOR-swizzled
// GEMM format), V^T staged from pre-transposed VtG (4 key-groups, [64][32]).
// All staging via global_load_lds (no VALU, no scalar LDS writes).
// P per-wave in the same swizzled format (b64 writes / b128 reads).
// Fragment<->MFMA mappings identical to the pass-verified r7/r8 kernel.
// ---------------------------------------------------------------------------
__global__ __launch_bounds__(256) void attn_kernel(
    const u16* __restrict__ qkv, const u16* __restrict__ VtG,
    u16* __restrict__ outp)
{
  __shared__ u16 Ks[2][128 * 32];   // [d-half][key-row][32] swizzled
  __shared__ u16 Vt[4][64 * 32];    // [key-group][d-row][32] swizzled
  __shared__ u16 Pl[4][2048];       // [wave][kh][16][32] swizzled
  const int t = threadIdx.x;
  const int lane = t & 63;
  const int wave = t >> 6;
  const int l15 = lane & 15;
  const int quad = lane >> 4;
  const int sw = quad ^ ((l15 >> 1) & 3);
  const int pair = blockIdx.x;          // 0..15
  const int bh = blockIdx.y;            // 0..31
  const int b = bh >> 4, h = bh & 15;
  const size_t srow = (size_t)b * 2048;
  const int rr = lane >> 2, qs = (lane & 3) ^ ((lane >> 3) & 3);
  u16* plw = Pl[wave];

  for (int tsel = 0; tsel < 2; tsel++) {
    const int qt = tsel ? 31 - pair : pair;
    const int tq0 = qt * 64;
    const int q = tq0 + wave * 16 + l15;

    short8 qf[2];
    {
      const size_t qbase = (srow + q) * 3072 + h * 64;
#pragma unroll
      for (int dh = 0; dh < 2; dh++) {
        int4 raw = *(const int4*)(qkv + qbase + dh * 32 + quad * 8);
        const u16* rp = (const u16*)&raw;
        short8 f;
#pragma unroll
        for (int j = 0; j < 8; j++)
          ((u16*)&f)[j] = f2bf(bf2f(rp[j]) * 0.125f);
        qf[dh] = f;
      }
    }

    float m_i = -INFINITY, l_i = 0.f;
    float4v accO[4] = {};
    const int nc = (qt + 2) >> 1;

    for (int ic = 0; ic < nc; ic++) {
      const int c0 = ic * 128;
      // ---- stage K (waves 0,1) and V^T (waves 2,3): 8 DMA issues each ----
#pragma unroll
      for (int k = 0; k < 8; k++) {
        const int I = wave * 8 + k;
        if (I < 16) {
          const int half = I >> 3, rb = (I & 7) * 16, row = rb + rr;
          gload_lds16(qkv + (srow + c0 + row) * 3072 + 1024 + h * 64 + half * 32 + qs * 8,
                      &Ks[half][rb * 32]);
        } else {
          const int g = (I - 16) >> 2, rb = ((I - 16) & 3) * 16, row = rb + rr;
          gload_lds16(VtG + ((size_t)bh * 64 + row) * 2048 + c0 + g * 32 + qs * 8,
                      &Vt[g][rb * 32]);
        }
      }
      __syncthreads();

      // ---- S^T[key][q] = K * Q^T : 8 key-subtiles x 2 d-halves ----
      float4v accS[8];
#pragma unroll
      for (int ks = 0; ks < 8; ks++) {
        short8 kf0 = *(const short8*)(&Ks[0][((ks * 16 + l15) * 4 + sw) * 8]);
        short8 kf1 = *(const short8*)(&Ks[1][((ks * 16 + l15) * 4 + sw) * 8]);
        float4v z = {};
        z = __builtin_amdgcn_mfma_f32_16x16x32_bf16(kf0, qf[0], z, 0, 0, 0);
        accS[ks] = __builtin_amdgcn_mfma_f32_16x16x32_bf16(kf1, qf[1], z, 0, 0, 0);
      }

      if (ic == nc - 1) {
#pragma unroll
        for (int ks = 0; ks < 8; ks++)
#pragma unroll
          for (int r = 0; r < 4; r++)
            if (c0 + ks * 16 + quad * 4 + r > q) accS[ks][r] = -INFINITY;
      }

      // ---- online softmax (per-lane scalar state) ----
      float cmax = -INFINITY;
#pragma unroll
      for (int ks = 0; ks < 8; ks++)
#pragma unroll
        for (int r = 0; r < 4; r++) cmax = fmaxf(cmax, accS[ks][r]);
      cmax = fmaxf(cmax, __shfl_xor(cmax, 16));
      cmax = fmaxf(cmax, __shfl_xor(cmax, 32));
      const float mn = fmaxf(m_i, cmax);
      const float alpha = __expf(m_i - mn);

      float psum = 0.f;
#pragma unroll
      for (int ks = 0; ks < 8; ks++) {
        float p0 = __expf(accS[ks][0] - mn);
        float p1 = __expf(accS[ks][1] - mn);
        float p2 = __expf(accS[ks][2] - mn);
        float p3 = __expf(accS[ks][3] - mn);
        psum += (p0 + p1) + (p2 + p3);
        u16x4 pk;
        pk.x = f2bf(p0); pk.y = f2bf(p1); pk.z = f2bf(p2); pk.w = f2bf(p3);
        const int seg = ((ks & 1) * 2 + (quad >> 1)) ^ ((l15 >> 1) & 3);
        *(u16x4*)(&plw[(ks >> 1) * 512 + (l15 * 4 + seg) * 8 + (quad & 1) * 4]) = pk;
      }
      psum += __shfl_xor(psum, 16);
      psum += __shfl_xor(psum, 32);
      l_i = l_i * alpha + psum;
      m_i = mn;
#pragma unroll
      for (int ds = 0; ds < 4; ds++)
#pragma unroll
        for (int r = 0; r < 4; r++) accO[ds][r] *= alpha;

      __threadfence_block();

      // ---- O^T[d][q] += V^T * P^T : 4 key-groups x 4 d-subtiles ----
#pragma unroll
      for (int kh = 0; kh < 4; kh++) {
        short8 pf = *(const short8*)(&plw[kh * 512 + (l15 * 4 + sw) * 8]);
#pragma unroll
        for (int ds = 0; ds < 4; ds++) {
          short8 vf = *(const short8*)(&Vt[kh][((ds * 16 + l15) * 4 + sw) * 8]);
          accO[ds] = __builtin_amdgcn_mfma_f32_16x16x32_bf16(vf, pf, accO[ds], 0, 0, 0);
        }
      }
      __syncthreads();
    }

    const float invl = 1.f / l_i;
    const size_t obase = (srow + q) * 1024 + h * 64;
#pragma unroll
    for (int ds = 0; ds < 4; ds++) {
      u16x4 pk;
      pk.x = f2bf(accO[ds][0] * invl);
      pk.y = f2bf(accO[ds][1] * invl);
      pk.z = f2bf(accO[ds][2] * invl);
      pk.w = f2bf(accO[ds][3] * invl);
      *(u16x4*)(outp + obase + ds * 16 + quad * 4) = pk;
    }
  }
}

// ---------------------------------------------------------------------------
// RMSNorm — UNCHANGED from r8.
// ---------------------------------------------------------------------------
template <bool XF32>
__global__ __launch_bounds__(256) void rmsnorm_kernel(
    const void* __restrict__ xv, const float* __restrict__ g, u16* __restrict__ o)
{
  const int row = blockIdx.x;
  const int t = threadIdx.x;
  float f0, f1, f2, f3;
  if (XF32) {
    float4 v = *(const float4*)((const float*)xv + (size_t)row * 1024 + t * 4);
    f0 = v.x; f1 = v.y; f2 = v.z; f3 = v.w;
  } else {
    int2 v = *(const int2*)((const u16*)xv + (size_t)row * 1024 + t * 4);
    const u16* p = (const u16*)&v;
    f0 = bf2f(p[0]); f1 = bf2f(p[1]); f2 = bf2f(p[2]); f3 = bf2f(p[3]);
  }
  float ss = f0 * f0 + f1 * f1 + f2 * f2 + f3 * f3;
#pragma unroll
  for (int off = 32; off > 0; off >>= 1) ss += __shfl_down(ss, off);
  __shared__ float red[4];
  if ((t & 63) == 0) red[t >> 6] = ss;
  __syncthreads();
  const float tot = red[0] + red[1] + red[2] + red[3];
  const float inv = rsqrtf(tot * (1.0f / 1024.0f) + 1e-5f);
  float4 gv = *(const float4*)(g + t * 4);
  u16x4 ov;
  ov.x = f2bf(f0 * gv.x * inv);
  ov.y = f2bf(f1 * gv.y * inv);
  ov.z = f2bf(f2 * gv.z * inv);
  ov.w = f2bf(f3 * gv.w * inv);
  *(u16x4*)(o + (size_t)row * 1024 + t * 4) = ov;
}

// ---------------------------------------------------------------------------
// Inputs (fp32): x wqkv wo g1 g2 w1 w2 w3. OUTPUT fp32.
// ws (72 MB): bf16 weights 24 + S1 8 (xn->att->xn2) + S2 24 (qkv->h)
// + S3 8 (x1) + VtG 8.
// ---------------------------------------------------------------------------
extern "C" void kernel_launch(void* const* d_in, const int* in_sizes, int n_in,
                              void* d_out, int out_size, void* d_ws, size_t ws_size,
                              hipStream_t stream)
{
  const float* x    = (const float*)d_in[0];
  const float* wqkv = (const float*)d_in[1];
  const float* wo   = (const float*)d_in[2];
  const float* g1   = (const float*)d_in[3];
  const float* g2   = (const float*)d_in[4];
  const float* w1   = (const float*)d_in[5];
  const float* w2   = (const float*)d_in[6];
  const float* w3   = (const float*)d_in[7];
  float* out = (float*)d_out;
  char* ws = (char*)d_ws;
  (void)in_sizes; (void)n_in; (void)out_size; (void)ws_size;

  size_t off = 0;
  auto alloc = [&](size_t bytes) { void* p = ws + off; off += (bytes + 255) & ~(size_t)255; return p; };
  u16* wqkvb = (u16*)alloc((size_t)3072 * 1024 * 2);
  u16* wob   = (u16*)alloc((size_t)1024 * 1024 * 2);
  u16* w1b   = (u16*)alloc((size_t)2688 * 1024 * 2);
  u16* w2b   = (u16*)alloc((size_t)2688 * 1024 * 2);
  u16* w3b   = (u16*)alloc((size_t)2688 * 1024 * 2);
  u16* S1    = (u16*)alloc((size_t)4096 * 1024 * 2);
  u16* S2    = (u16*)alloc((size_t)4096 * 3072 * 2);
  u16* S3    = (u16*)alloc((size_t)4096 * 1024 * 2);
  u16* VtG   = (u16*)alloc((size_t)32 * 64 * 2048 * 2);

  PrepArgs pa;
  const float* srcs[5] = {wqkv, wo, w1, w2, w3};
  u16* dsts[5] = {wqkvb, wob, w1b, w2b, w3b};
  const int nelem[5] = {3072 * 1024, 1024 * 1024, 2688 * 1024, 2688 * 1024, 2688 * 1024};
  int pre = 0;
  for (int i = 0; i < 5; i++) {
    pa.src[i] = srcs[i];
    pa.dst[i] = dsts[i];
    pa.pre[i] = pre;
    pre += nelem[i] / 8;
  }
  pa.pre[5] = pre;
  prep_kernel<<<(pre + 255) / 256, 256, 0, stream>>>(pa);

  rmsnorm_kernel<true><<<4096, 256, 0, stream>>>(x, g1, S1);                        // xn
  gemm_bt_kernel<0, false, 128><<<dim3(24, 32), 256, 0, stream>>>(S1, wqkvb, S2,
                                                  nullptr, 4096, 3072, 1024);       // qkv
  vtrans_kernel<<<dim3(32, 32), 256, 0, stream>>>(S2, VtG);                         // V^T
  attn_kernel<<<dim3(16, 32), 256, 0, stream>>>(S2, VtG, S1);                       // att
  gemm_bt_kernel<1, false, 64><<<dim3(16, 32), 256, 0, stream>>>(S1, wob, S3, x,
                                                  4096, 1024, 1024);                // x1
  rmsnorm_kernel<false><<<4096, 256, 0, stream>>>(S3, g2, S1);                      // xn2
  gemm_w13_kernel<<<dim3(21, 32), 256, 0, stream>>>(S1, w1b, w3b, S2,
                                                  4096, 2688, 1024);                // h
  gemm_bt_kernel<2, true, 64><<<dim3(16, 32), 256, 0, stream>>>(S2, w2b, out, S3,
                                                  4096, 1024, 2688);                // out fp32
}

// Round 10
// 354.448 us; speedup vs baseline: 1.6593x; 1.1359x over previous
//
#include <hip/hip_runtime.h>
#include <cstdint>
#include <cstddef>

typedef unsigned short u16;
typedef __attribute__((ext_vector_type(8))) short short8;
typedef __attribute__((ext_vector_type(4))) float float4v;

struct alignas(8) u16x4 { u16 x, y, z, w; };

__device__ __forceinline__ float bf2f(u16 u) {
  union { uint32_t i; float f; } x;
  x.i = ((uint32_t)u) << 16;
  return x.f;
}
__device__ __forceinline__ u16 f2bf(float f) {
  union { float f; uint32_t i; } x;
  x.f = f;
  uint32_t r = x.i + 0x7fffu + ((x.i >> 16) & 1u);  // RNE
  return (u16)(r >> 16);
}
__device__ __forceinline__ int4 pack8(const float4& a, const float4& b) {
  int4 r;
  r.x = (uint32_t)f2bf(a.x) | ((uint32_t)f2bf(a.y) << 16);
  r.y = (uint32_t)f2bf(a.z) | ((uint32_t)f2bf(a.w) << 16);
  r.z = (uint32_t)f2bf(b.x) | ((uint32_t)f2bf(b.y) << 16);
  r.w = (uint32_t)f2bf(b.z) | ((uint32_t)f2bf(b.w) << 16);
  return r;
}

// async global->LDS, 16 B per lane; LDS dest = wave-uniform base + lane*16.
__device__ __forceinline__ void gload_lds16(const void* g, void* l) {
  __builtin_amdgcn_global_load_lds(
      (const __attribute__((address_space(1))) void*)g,
      (__attribute__((address_space(3))) void*)l, 16, 0, 0);
}

// ---------------------------------------------------------------------------
// Weight prep: fp32 -> bf16 for the 5 weight matrices. UNCHANGED.
// ---------------------------------------------------------------------------
struct PrepArgs {
  const float* src[5];
  u16* dst[5];
  int pre[6];
};

__global__ __launch_bounds__(256) void prep_kernel(PrepArgs a)
{
  const int g = blockIdx.x * 256 + threadIdx.x;
  if (g >= a.pre[5]) return;
  int t = 0;
#pragma unroll
  for (int i = 0; i < 5; i++) if (g >= a.pre[i + 1]) t = i + 1;
  const int idx = (g - a.pre[t]) * 8;
  const float* s = a.src[t] + idx;
  float4 v0 = *(const float4*)(s);
  float4 v1 = *(const float4*)(s + 4);
  *(int4*)(a.dst[t] + idx) = pack8(v0, v1);
}

// ---------------------------------------------------------------------------
// GEMM_BT — UNCHANGED from r8/r9 (m97 structure, global_load_lds, XOR swizzle).
// ---------------------------------------------------------------------------
template <int RMODE, bool OUTF32, int TN>
__global__ __launch_bounds__(256) void gemm_bt_kernel(
    const u16* __restrict__ A, const u16* __restrict__ B,
    void* __restrict__ Cv, const void* __restrict__ Rv,
    int M, int N, int K)
{
  constexpr int JN = TN / 32;
  __shared__ u16 As[128 * 32];
  __shared__ u16 Bs[TN * 32];
  const int t = threadIdx.x;
  const int lane = t & 63;
  const int wave = t >> 6;
  const int l15 = lane & 15;
  const int quad = lane >> 4;
  const int wm = (wave >> 1) * 64;
  const int wn = (wave & 1) * (TN / 2);
  const int m0 = blockIdx.y * 128;
  const int n0 = blockIdx.x * TN;
  const int sw = quad ^ ((l15 >> 1) & 3);

  float4v acc[4][JN] = {};

  const int r0 = t >> 2, q0s = (t & 3) ^ ((t >> 3) & 3);
  const int s1 = 256 + t;
  const int r1 = s1 >> 2, q1s = (s1 & 3) ^ ((s1 >> 3) & 3);

  for (int kk = 0; kk < K; kk += 32) {
    gload_lds16(A + (size_t)(m0 + r0) * K + kk + q0s * 8, &As[(wave * 64) * 8]);
    gload_lds16(A + (size_t)(m0 + r1) * K + kk + q1s * 8, &As[(256 + wave * 64) * 8]);
    gload_lds16(B + (size_t)(n0 + r0) * K + kk + q0s * 8, &Bs[(wave * 64) * 8]);
    if (TN == 128)
      gload_lds16(B + (size_t)(n0 + r1) * K + kk + q1s * 8, &Bs[(256 + wave * 64) * 8]);
    __syncthreads();
    short8 af[4], bf[JN];
#pragma unroll
    for (int i = 0; i < 4; i++)
      af[i] = *(const short8*)(&As[((wm + i * 16 + l15) * 4 + sw) * 8]);
#pragma unroll
    for (int j = 0; j < JN; j++)
      bf[j] = *(const short8*)(&Bs[((wn + j * 16 + l15) * 4 + sw) * 8]);
#pragma unroll
    for (int i = 0; i < 4; i++)
#pragma unroll
      for (int j = 0; j < JN; j++)
        acc[i][j] = __builtin_amdgcn_mfma_f32_16x16x32_bf16(af[i], bf[j], acc[i][j], 0, 0, 0);
    __syncthreads();
  }

#pragma unroll
  for (int i = 0; i < 4; i++) {
#pragma unroll
    for (int r = 0; r < 4; r++) {
      const int row = m0 + wm + i * 16 + quad * 4 + r;
      const size_t base = (size_t)row * N;
#pragma unroll
      for (int j = 0; j < JN; j++) {
        const int col = n0 + wn + j * 16 + l15;
        float v = acc[i][j][r];
        if (RMODE == 1) v += ((const float*)Rv)[base + col];
        if (RMODE == 2) v += bf2f(((const u16*)Rv)[base + col]);
        if (OUTF32) ((float*)Cv)[base + col] = v;
        else        ((u16*)Cv)[base + col] = f2bf(v);
      }
    }
  }
}

// ---------------------------------------------------------------------------
// Fused FFN up-projection, r10: 128x64 tile (TN=64) -> grid 42x32 = 1344
// blocks (5.25/CU vs 2.6 before) and acc VGPRs 128->64 (occupancy breakpoint
// at 128, m69). Staging:MFMA stays 1KB/MFMA (A 8KB + B1/B2 4KB each per
// K-step / 16 MFMA). Per-output arithmetic identical to r9.
// ---------------------------------------------------------------------------
__global__ __launch_bounds__(256) void gemm_w13_kernel(
    const u16* __restrict__ A, const u16* __restrict__ B1,
    const u16* __restrict__ B2, u16* __restrict__ C,
    int M, int N, int K)
{
  __shared__ u16 As[128 * 32];
  __shared__ u16 B1s[64 * 32];
  __shared__ u16 B2s[64 * 32];
  const int t = threadIdx.x;
  const int lane = t & 63;
  const int wave = t >> 6;
  const int l15 = lane & 15;
  const int quad = lane >> 4;
  const int wm = (wave >> 1) * 64;
  const int wn = (wave & 1) * 32;
  const int m0 = blockIdx.y * 128;
  const int n0 = blockIdx.x * 64;
  const int sw = quad ^ ((l15 >> 1) & 3);

  float4v accA[4][2] = {};
  float4v accB[4][2] = {};

  const int r0 = t >> 2, q0s = (t & 3) ^ ((t >> 3) & 3);
  const int s1 = 256 + t;
  const int r1 = s1 >> 2, q1s = (s1 & 3) ^ ((s1 >> 3) & 3);

  for (int kk = 0; kk < K; kk += 32) {
    gload_lds16(A + (size_t)(m0 + r0) * K + kk + q0s * 8, &As[(wave * 64) * 8]);
    gload_lds16(A + (size_t)(m0 + r1) * K + kk + q1s * 8, &As[(256 + wave * 64) * 8]);
    gload_lds16(B1 + (size_t)(n0 + r0) * K + kk + q0s * 8, &B1s[(wave * 64) * 8]);
    gload_lds16(B2 + (size_t)(n0 + r0) * K + kk + q0s * 8, &B2s[(wave * 64) * 8]);
    __syncthreads();
    short8 af[4], b1f[2], b2f[2];
#pragma unroll
    for (int i = 0; i < 4; i++)
      af[i] = *(const short8*)(&As[((wm + i * 16 + l15) * 4 + sw) * 8]);
#pragma unroll
    for (int j = 0; j < 2; j++) {
      b1f[j] = *(const short8*)(&B1s[((wn + j * 16 + l15) * 4 + sw) * 8]);
      b2f[j] = *(const short8*)(&B2s[((wn + j * 16 + l15) * 4 + sw) * 8]);
    }
#pragma unroll
    for (int i = 0; i < 4; i++)
#pragma unroll
      for (int j = 0; j < 2; j++) {
        accA[i][j] = __builtin_amdgcn_mfma_f32_16x16x32_bf16(af[i], b1f[j], accA[i][j], 0, 0, 0);
        accB[i][j] = __builtin_amdgcn_mfma_f32_16x16x32_bf16(af[i], b2f[j], accB[i][j], 0, 0, 0);
      }
    __syncthreads();
  }

#pragma unroll
  for (int i = 0; i < 4; i++) {
#pragma unroll
    for (int r = 0; r < 4; r++) {
      const int row = m0 + wm + i * 16 + quad * 4 + r;
      const size_t base = (size_t)row * N;
#pragma unroll
      for (int j = 0; j < 2; j++) {
        const int col = n0 + wn + j * 16 + l15;
        float a = accA[i][j][r];
        float b = accB[i][j][r];
        float h = a / (1.f + __expf(-a)) * b;
        C[base + col] = f2bf(h);
      }
    }
  }
}

// ---------------------------------------------------------------------------
// V transpose — UNCHANGED from r9.
// ---------------------------------------------------------------------------
__global__ __launch_bounds__(256) void vtrans_kernel(
    const u16* __restrict__ qkv, u16* __restrict__ VtG)
{
  __shared__ u16 T[64 * 72];
  const int t = threadIdx.x;
  const int s0 = blockIdx.x * 64;
  const int bh = blockIdx.y, b = bh >> 4, h = bh & 15;
  {
    const int sl = t >> 2, dseg = (t & 3) * 16;
    const size_t src = ((size_t)b * 2048 + s0 + sl) * 3072 + 2048 + h * 64 + dseg;
    int4 v0 = *(const int4*)(qkv + src);
    int4 v1 = *(const int4*)(qkv + src + 8);
    *(int4*)(&T[sl * 72 + dseg]) = v0;
    *(int4*)(&T[sl * 72 + dseg + 8]) = v1;
  }
  __syncthreads();
  {
    const int d = t >> 2, sseg = (t & 3) * 16;
    alignas(16) u16 buf[16];
#pragma unroll
    for (int i = 0; i < 16; i++) buf[i] = T[(sseg + i) * 72 + d];
    u16* dst = VtG + ((size_t)bh * 64 + d) * 2048 + s0 + sseg;
    *(int4*)(dst) = *(const int4*)(&buf[0]);
    *(int4*)(dst + 8) = *(const int4*)(&buf[8]);
  }
}

// ---------------------------------------------------------------------------
// Causal flash attention v2 — UNCHANGED from r9.
// ---------------------------------------------------------------------------
__global__ __launch_bounds__(256) void attn_kernel(
    const u16* __restrict__ qkv, const u16* __restrict__ VtG,
    u16* __restrict__ outp)
{
  __shared__ u16 Ks[2][128 * 32];
  __shared__ u16 Vt[4][64 * 32];
  __shared__ u16 Pl[4][2048];
  const int t = threadIdx.x;
  const int lane = t & 63;
  const int wave = t >> 6;
  const int l15 = lane & 15;
  const int quad = lane >> 4;
  const int sw = quad ^ ((l15 >> 1) & 3);
  const int pair = blockIdx.x;
  const int bh = blockIdx.y;
  const int b = bh >> 4, h = bh & 15;
  const size_t srow = (size_t)b * 2048;
  const int rr = lane >> 2, qs = (lane & 3) ^ ((lane >> 3) & 3);
  u16* plw = Pl[wave];

  for (int tsel = 0; tsel < 2; tsel++) {
    const int qt = tsel ? 31 - pair : pair;
    const int tq0 = qt * 64;
    const int q = tq0 + wave * 16 + l15;

    short8 qf[2];
    {
      const size_t qbase = (srow + q) * 3072 + h * 64;
#pragma unroll
      for (int dh = 0; dh < 2; dh++) {
        int4 raw = *(const int4*)(qkv + qbase + dh * 32 + quad * 8);
        const u16* rp = (const u16*)&raw;
        short8 f;
#pragma unroll
        for (int j = 0; j < 8; j++)
          ((u16*)&f)[j] = f2bf(bf2f(rp[j]) * 0.125f);
        qf[dh] = f;
      }
    }

    float m_i = -INFINITY, l_i = 0.f;
    float4v accO[4] = {};
    const int nc = (qt + 2) >> 1;

    for (int ic = 0; ic < nc; ic++) {
      const int c0 = ic * 128;
#pragma unroll
      for (int k = 0; k < 8; k++) {
        const int I = wave * 8 + k;
        if (I < 16) {
          const int half = I >> 3, rb = (I & 7) * 16, row = rb + rr;
          gload_lds16(qkv + (srow + c0 + row) * 3072 + 1024 + h * 64 + half * 32 + qs * 8,
                      &Ks[half][rb * 32]);
        } else {
          const int g = (I - 16) >> 2, rb = ((I - 16) & 3) * 16, row = rb + rr;
          gload_lds16(VtG + ((size_t)bh * 64 + row) * 2048 + c0 + g * 32 + qs * 8,
                      &Vt[g][rb * 32]);
        }
      }
      __syncthreads();

      float4v accS[8];
#pragma unroll
      for (int ks = 0; ks < 8; ks++) {
        short8 kf0 = *(const short8*)(&Ks[0][((ks * 16 + l15) * 4 + sw) * 8]);
        short8 kf1 = *(const short8*)(&Ks[1][((ks * 16 + l15) * 4 + sw) * 8]);
        float4v z = {};
        z = __builtin_amdgcn_mfma_f32_16x16x32_bf16(kf0, qf[0], z, 0, 0, 0);
        accS[ks] = __builtin_amdgcn_mfma_f32_16x16x32_bf16(kf1, qf[1], z, 0, 0, 0);
      }

      if (ic == nc - 1) {
#pragma unroll
        for (int ks = 0; ks < 8; ks++)
#pragma unroll
          for (int r = 0; r < 4; r++)
            if (c0 + ks * 16 + quad * 4 + r > q) accS[ks][r] = -INFINITY;
      }

      float cmax = -INFINITY;
#pragma unroll
      for (int ks = 0; ks < 8; ks++)
#pragma unroll
        for (int r = 0; r < 4; r++) cmax = fmaxf(cmax, accS[ks][r]);
      cmax = fmaxf(cmax, __shfl_xor(cmax, 16));
      cmax = fmaxf(cmax, __shfl_xor(cmax, 32));
      const float mn = fmaxf(m_i, cmax);
      const float alpha = __expf(m_i - mn);

      float psum = 0.f;
#pragma unroll
      for (int ks = 0; ks < 8; ks++) {
        float p0 = __expf(accS[ks][0] - mn);
        float p1 = __expf(accS[ks][1] - mn);
        float p2 = __expf(accS[ks][2] - mn);
        float p3 = __expf(accS[ks][3] - mn);
        psum += (p0 + p1) + (p2 + p3);
        u16x4 pk;
        pk.x = f2bf(p0); pk.y = f2bf(p1); pk.z = f2bf(p2); pk.w = f2bf(p3);
        const int seg = ((ks & 1) * 2 + (quad >> 1)) ^ ((l15 >> 1) & 3);
        *(u16x4*)(&plw[(ks >> 1) * 512 + (l15 * 4 + seg) * 8 + (quad & 1) * 4]) = pk;
      }
      psum += __shfl_xor(psum, 16);
      psum += __shfl_xor(psum, 32);
      l_i = l_i * alpha + psum;
      m_i = mn;
#pragma unroll
      for (int ds = 0; ds < 4; ds++)
#pragma unroll
        for (int r = 0; r < 4; r++) accO[ds][r] *= alpha;

      __threadfence_block();

#pragma unroll
      for (int kh = 0; kh < 4; kh++) {
        short8 pf = *(const short8*)(&plw[kh * 512 + (l15 * 4 + sw) * 8]);
#pragma unroll
        for (int ds = 0; ds < 4; ds++) {
          short8 vf = *(const short8*)(&Vt[kh][((ds * 16 + l15) * 4 + sw) * 8]);
          accO[ds] = __builtin_amdgcn_mfma_f32_16x16x32_bf16(vf, pf, accO[ds], 0, 0, 0);
        }
      }
      __syncthreads();
    }

    const float invl = 1.f / l_i;
    const size_t obase = (srow + q) * 1024 + h * 64;
#pragma unroll
    for (int ds = 0; ds < 4; ds++) {
      u16x4 pk;
      pk.x = f2bf(accO[ds][0] * invl);
      pk.y = f2bf(accO[ds][1] * invl);
      pk.z = f2bf(accO[ds][2] * invl);
      pk.w = f2bf(accO[ds][3] * invl);
      *(u16x4*)(outp + obase + ds * 16 + quad * 4) = pk;
    }
  }
}

// ---------------------------------------------------------------------------
// RMSNorm — UNCHANGED.
// ---------------------------------------------------------------------------
template <bool XF32>
__global__ __launch_bounds__(256) void rmsnorm_kernel(
    const void* __restrict__ xv, const float* __restrict__ g, u16* __restrict__ o)
{
  const int row = blockIdx.x;
  const int t = threadIdx.x;
  float f0, f1, f2, f3;
  if (XF32) {
    float4 v = *(const float4*)((const float*)xv + (size_t)row * 1024 + t * 4);
    f0 = v.x; f1 = v.y; f2 = v.z; f3 = v.w;
  } else {
    int2 v = *(const int2*)((const u16*)xv + (size_t)row * 1024 + t * 4);
    const u16* p = (const u16*)&v;
    f0 = bf2f(p[0]); f1 = bf2f(p[1]); f2 = bf2f(p[2]); f3 = bf2f(p[3]);
  }
  float ss = f0 * f0 + f1 * f1 + f2 * f2 + f3 * f3;
#pragma unroll
  for (int off = 32; off > 0; off >>= 1) ss += __shfl_down(ss, off);
  __shared__ float red[4];
  if ((t & 63) == 0) red[t >> 6] = ss;
  __syncthreads();
  const float tot = red[0] + red[1] + red[2] + red[3];
  const float inv = rsqrtf(tot * (1.0f / 1024.0f) + 1e-5f);
  float4 gv = *(const float4*)(g + t * 4);
  u16x4 ov;
  ov.x = f2bf(f0 * gv.x * inv);
  ov.y = f2bf(f1 * gv.y * inv);
  ov.z = f2bf(f2 * gv.z * inv);
  ov.w = f2bf(f3 * gv.w * inv);
  *(u16x4*)(o + (size_t)row * 1024 + t * 4) = ov;
}

// ---------------------------------------------------------------------------
// Inputs (fp32): x wqkv wo g1 g2 w1 w2 w3. OUTPUT fp32.
// ws (72 MB): bf16 weights 24 + S1 8 + S2 24 + S3 8 + VtG 8.
// ---------------------------------------------------------------------------
extern "C" void kernel_launch(void* const* d_in, const int* in_sizes, int n_in,
                              void* d_out, int out_size, void* d_ws, size_t ws_size,
                              hipStream_t stream)
{
  const float* x    = (const float*)d_in[0];
  const float* wqkv = (const float*)d_in[1];
  const float* wo   = (const float*)d_in[2];
  const float* g1   = (const float*)d_in[3];
  const float* g2   = (const float*)d_in[4];
  const float* w1   = (const float*)d_in[5];
  const float* w2   = (const float*)d_in[6];
  const float* w3   = (const float*)d_in[7];
  float* out = (float*)d_out;
  char* ws = (char*)d_ws;
  (void)in_sizes; (void)n_in; (void)out_size; (void)ws_size;

  size_t off = 0;
  auto alloc = [&](size_t bytes) { void* p = ws + off; off += (bytes + 255) & ~(size_t)255; return p; };
  u16* wqkvb = (u16*)alloc((size_t)3072 * 1024 * 2);
  u16* wob   = (u16*)alloc((size_t)1024 * 1024 * 2);
  u16* w1b   = (u16*)alloc((size_t)2688 * 1024 * 2);
  u16* w2b   = (u16*)alloc((size_t)2688 * 1024 * 2);
  u16* w3b   = (u16*)alloc((size_t)2688 * 1024 * 2);
  u16* S1    = (u16*)alloc((size_t)4096 * 1024 * 2);
  u16* S2    = (u16*)alloc((size_t)4096 * 3072 * 2);
  u16* S3    = (u16*)alloc((size_t)4096 * 1024 * 2);
  u16* VtG   = (u16*)alloc((size_t)32 * 64 * 2048 * 2);

  PrepArgs pa;
  const float* srcs[5] = {wqkv, wo, w1, w2, w3};
  u16* dsts[5] = {wqkvb, wob, w1b, w2b, w3b};
  const int nelem[5] = {3072 * 1024, 1024 * 1024, 2688 * 1024, 2688 * 1024, 2688 * 1024};
  int pre = 0;
  for (int i = 0; i < 5; i++) {
    pa.src[i] = srcs[i];
    pa.dst[i] = dsts[i];
    pa.pre[i] = pre;
    pre += nelem[i] / 8;
  }
  pa.pre[5] = pre;
  prep_kernel<<<(pre + 255) / 256, 256, 0, stream>>>(pa);

  rmsnorm_kernel<true><<<4096, 256, 0, stream>>>(x, g1, S1);                        // xn
  gemm_bt_kernel<0, false, 128><<<dim3(24, 32), 256, 0, stream>>>(S1, wqkvb, S2,
                                                  nullptr, 4096, 3072, 1024);       // qkv
  vtrans_kernel<<<dim3(32, 32), 256, 0, stream>>>(S2, VtG);                         // V^T
  attn_kernel<<<dim3(16, 32), 256, 0, stream>>>(S2, VtG, S1);                       // att
  gemm_bt_kernel<1, false, 64><<<dim3(16, 32), 256, 0, stream>>>(S1, wob, S3, x,
                                                  4096, 1024, 1024);                // x1
  rmsnorm_kernel<false><<<4096, 256, 0, stream>>>(S3, g2, S1);                      // xn2
  gemm_w13_kernel<<<dim3(42, 32), 256, 0, stream>>>(S1, w1b, w3b, S2,
                                                  4096, 2688, 1024);                // h
  gemm_bt_kernel<2, true, 64><<<dim3(16, 32), 256, 0, stream>>>(S2, w2b, out, S3,
                                                  4096, 1024, 2688);                // out fp32
}